// Round 8
// baseline (323.630 us; speedup 1.0000x reference)
//
#include <hip/hip_runtime.h>
#include <hip/hip_bf16.h>
#include <stdint.h>

#define NEXP 64
#define TTOK 32768
#define HID  1024
#define IMID 512
#define CAP  1024

typedef __bf16 bf16x8 __attribute__((ext_vector_type(8)));
typedef float  f32x4  __attribute__((ext_vector_type(4)));

static __device__ __forceinline__ unsigned int f2bf_u(float f) {
    __hip_bfloat16 h = __float2bfloat16(f);
    return (unsigned int)*reinterpret_cast<unsigned short*>(&h);
}
static __device__ __forceinline__ unsigned int pack2(float lo, float hi) {
    return f2bf_u(lo) | (f2bf_u(hi) << 16);
}
static __device__ __forceinline__ unsigned short f2bf_s(float f) {
    __hip_bfloat16 h = __float2bfloat16(f);
    return *reinterpret_cast<unsigned short*>(&h);
}

static __device__ __forceinline__ void gload16(const void* g, void* l) {
    __builtin_amdgcn_global_load_lds(
        (const __attribute__((address_space(1))) unsigned int*)g,
        (__attribute__((address_space(3))) unsigned int*)l,
        16, 0, 0);
}

// wave-parallel exclusive prefix: sum of tpe[i] for i < e
static __device__ __forceinline__ int expert_start(const int* tpe, int e, int lane) {
    int v = tpe[lane];
    int contrib = (lane < e) ? v : 0;
    #pragma unroll
    for (int off = 1; off < 64; off <<= 1)
        contrib += __shfl_xor(contrib, off, 64);
    return contrib;
}

// ================= merged conversion kernel =================
// blocks [0, 2048): w13 transpose-convert, 8 tiles each (16384 tiles total)
//   fp32 [e][1024k][1024n] -> bf16 [e][np][1024k],
//   np = (icol>>5)*64 + isup*32 + (icol&31), icol=n&511, isup=n>>9
// blocks [2048, 4096): x convert, grid-strided
//   fp32 [T,1024] -> bf16, 64 floats per thread per pass, 8 passes
__global__ __launch_bounds__(256)
void cvt_all_k(const float* __restrict__ x, unsigned short* __restrict__ xbf,
               const float* __restrict__ w13, unsigned short* __restrict__ w13p) {
    const int bid = blockIdx.x;
    const int t   = threadIdx.x;

    if (bid < 2048) {
        __shared__ unsigned short Tl[64][72];
        #pragma unroll 1
        for (int j = 0; j < 8; ++j) {
            const int tile = bid * 8 + j;            // 0..16383
            const int n0 = (tile & 15) * 64;
            const int k0 = ((tile >> 4) & 15) * 64;
            const int e  = tile >> 8;
            const int kl = t >> 4, nl = (t & 15) * 4;
            const float* src = w13 + ((size_t)e << 20) + (size_t)k0 * 1024 + n0;
            #pragma unroll
            for (int p = 0; p < 4; ++p) {
                int k = kl + p * 16;
                f32x4 v = *reinterpret_cast<const f32x4*>(src + (size_t)k * 1024 + nl);
                uint2 wv; wv.x = pack2(v.x, v.y); wv.y = pack2(v.z, v.w);
                *reinterpret_cast<uint2*>(&Tl[k][nl]) = wv;
            }
            __syncthreads();
            const int nloc = t >> 2, kc = (t & 3) * 16;
            const int n = n0 + nloc;
            const int icol = n & 511, isup = n >> 9;
            const int np = (icol >> 5) * 64 + isup * 32 + (icol & 31);
            unsigned int v32[8];
            #pragma unroll
            for (int q = 0; q < 8; ++q)
                v32[q] = (unsigned int)Tl[kc + 2 * q][nloc] |
                         ((unsigned int)Tl[kc + 2 * q + 1][nloc] << 16);
            unsigned short* dst = w13p + ((size_t)e << 20) + (size_t)np * 1024 + k0 + kc;
            uint4 o0 = {v32[0], v32[1], v32[2], v32[3]};
            uint4 o1 = {v32[4], v32[5], v32[6], v32[7]};
            *reinterpret_cast<uint4*>(dst)     = o0;
            *reinterpret_cast<uint4*>(dst + 8) = o1;
            __syncthreads();
        }
    } else {
        // x: 33,554,432 floats; 2048 blocks x 256 thr x 64 floats
        const int xb = bid - 2048;
        size_t base = ((size_t)xb * 256 + t) * 64;
        #pragma unroll
        for (int p = 0; p < 8; ++p) {
            size_t i = base + p * 8;
            f32x4 a = *reinterpret_cast<const f32x4*>(x + i);
            f32x4 b = *reinterpret_cast<const f32x4*>(x + i + 4);
            uint4 o;
            o.x = pack2(a.x, a.y); o.y = pack2(a.z, a.w);
            o.z = pack2(b.x, b.y); o.w = pack2(b.z, b.w);
            *reinterpret_cast<uint4*>(xbf + i) = o;
        }
    }
}

// one 64x64 transpose-convert tile of w2: fp32 [e][512k][1024n] -> bf16 [e][n][512k]
static __device__ __forceinline__ void w2_tile_cvt(const float* __restrict__ w2,
                                                   unsigned short* __restrict__ w2p,
                                                   int tile, int t, char* lds) {
    const int e  = tile >> 7;
    const int k0 = ((tile >> 4) & 7) * 64;
    const int n0 = (tile & 15) * 64;
    unsigned short (*Tl)[72] = reinterpret_cast<unsigned short(*)[72]>(lds);  // 9216 B
    const int kl = t >> 4, nl = (t & 15) * 4;
    const float* src = w2 + (size_t)e * (IMID * HID) + (size_t)k0 * 1024 + n0;
    #pragma unroll
    for (int p = 0; p < 4; ++p) {
        int k = kl + p * 16;
        f32x4 v = *reinterpret_cast<const f32x4*>(src + (size_t)k * 1024 + nl);
        uint2 wv; wv.x = pack2(v.x, v.y); wv.y = pack2(v.z, v.w);
        *reinterpret_cast<uint2*>(&Tl[k][nl]) = wv;
    }
    __syncthreads();
    const int nloc = t >> 2, kc = (t & 3) * 16;
    unsigned int v32[8];
    #pragma unroll
    for (int j = 0; j < 8; ++j)
        v32[j] = (unsigned int)Tl[kc + 2 * j][nloc] |
                 ((unsigned int)Tl[kc + 2 * j + 1][nloc] << 16);
    unsigned short* dst = w2p + (size_t)e * (HID * IMID) + (size_t)(n0 + nloc) * IMID + k0 + kc;
    uint4 o0 = {v32[0], v32[1], v32[2], v32[3]};
    uint4 o1 = {v32[4], v32[5], v32[6], v32[7]};
    *reinterpret_cast<uint4*>(dst)     = o0;
    *reinterpret_cast<uint4*>(dst + 8) = o1;
}

// ================= GEMM1: xbf[cnt,1024] x w13p -> SwiGLU -> hbuf bf16 [T,512]
// 128x128 tile, BK=64, 4 waves (2x2), all staging via global_load_lds with
// both-sides XOR swizzle. Tail: each block converts 2 w2 tiles.
__global__ __launch_bounds__(256, 4)
void gemm1(const unsigned short* __restrict__ xbf,
           const int* __restrict__ tpe,
           const unsigned short* __restrict__ w13p,
           unsigned short* __restrict__ hbuf,
           const float* __restrict__ w2,
           unsigned short* __restrict__ w2p) {
    __shared__ alignas(16) char lds[32768];
    const int bid  = blockIdx.x;                 // 4096 blocks
    const int work = (bid & 7) * 512 + (bid >> 3);
    const int e  = work >> 6;                    // 0..63
    const int nt = (work >> 3) & 7;              // 0..7 : 128 n'-rows = 64 icols
    const int mt = work & 7;                     // 0..7

    const int t = threadIdx.x, lane = t & 63, w = t >> 6;
    int cnt = tpe[e]; if (cnt > CAP) cnt = CAP;
    const int m0 = mt * 128;
    const int start = expert_start(tpe, e, lane);

    if (m0 < cnt) {
        char* As = lds;            // [128m][64k] bf16, source-swizzled
        char* Bs = lds + 16384;    // [128n'][64k] bf16, source-swizzled
        const int wr = w >> 1, wc = w & 1;
        const int r = lane & 15, q = lane >> 4;

        f32x4 acc[4][4];
        const f32x4 z4 = {0.f, 0.f, 0.f, 0.f};
        #pragma unroll
        for (int i = 0; i < 4; ++i)
            #pragma unroll
            for (int j = 0; j < 4; ++j) acc[i][j] = z4;

        const int swb = ((lane & 7) ^ (lane >> 3)) << 4;
        const char* aP = (const char*)xbf;   // 2048 B rows
        const char* bP = (const char*)w13p + ((size_t)e << 21) + (size_t)(nt * 128) * 2048;

        for (int kt = 0; kt < 16; ++kt) {
            __syncthreads();
            const int kb = kt * 128;
            #pragma unroll
            for (int i = 0; i < 4; ++i) {
                const int srow = w * 32 + i * 8 + (lane >> 3);
                long ar = (long)start + m0 + srow;
                if (ar > TTOK - 1) ar = TTOK - 1;
                gload16(aP + ar * 2048 + kb + swb, As + w * 4096 + i * 1024);
                gload16(bP + (size_t)srow * 2048 + kb + swb, Bs + w * 4096 + i * 1024);
            }
            __syncthreads();
            #pragma unroll
            for (int kk = 0; kk < 2; ++kk) {
                bf16x8 af[4], bf[4];
                #pragma unroll
                for (int fm = 0; fm < 4; ++fm) {
                    int row = (wr << 6) + (fm << 4) + r;
                    af[fm] = *reinterpret_cast<const bf16x8*>(
                        As + row * 128 + ((kk * 64 + q * 16) ^ ((row & 7) << 4)));
                }
                #pragma unroll
                for (int fn = 0; fn < 4; ++fn) {
                    int row = (wc << 6) + (fn << 4) + r;
                    bf[fn] = *reinterpret_cast<const bf16x8*>(
                        Bs + row * 128 + ((kk * 64 + q * 16) ^ ((row & 7) << 4)));
                }
                #pragma unroll
                for (int fm = 0; fm < 4; ++fm)
                    #pragma unroll
                    for (int fn = 0; fn < 4; ++fn)
                        acc[fm][fn] = __builtin_amdgcn_mfma_f32_16x16x32_bf16(
                            af[fm], bf[fn], acc[fm][fn], 0, 0, 0);
            }
        }

        // SwiGLU: n' = nt*128 + wc*64 + fn*16 + r; fn<2 = gate, fn>=2 = up
        #pragma unroll
        for (int fm = 0; fm < 4; ++fm) {
            int mb = m0 + (wr << 6) + (fm << 4) + (q << 2);
            #pragma unroll
            for (int fp = 0; fp < 2; ++fp) {
                f32x4 g = acc[fm][fp];
                f32x4 u = acc[fm][fp + 2];
                int icol = (nt * 2 + wc) * 32 + fp * 16 + r;
                #pragma unroll
                for (int v = 0; v < 4; ++v) {
                    if (mb + v < cnt) {
                        float gv = g[v];
                        float sv = (gv / (1.f + __expf(-gv))) * u[v];
                        hbuf[(size_t)(start + mb + v) * IMID + icol] = f2bf_s(sv);
                    }
                }
            }
        }
    }

    // ---- tail: convert 2 w2 tiles (8192 tiles / 4096 blocks) ----
    __syncthreads();
    #pragma unroll 1
    for (int j = 0; j < 2; ++j) {
        w2_tile_cvt(w2, w2p, bid * 2 + j, t, lds);
        __syncthreads();
    }
}

// ================= GEMM2: hbuf[cnt,512] x w2p -> out fp32 [T,1024]
__global__ __launch_bounds__(256, 4)
void gemm2(const unsigned short* __restrict__ hbuf,
           const int* __restrict__ tpe,
           const unsigned short* __restrict__ w2p,
           float* __restrict__ out) {
    __shared__ alignas(16) char lds[32768];
    const int bid  = blockIdx.x;                 // 4096 blocks
    const int work = (bid & 7) * 512 + (bid >> 3);
    const int e  = work >> 6;
    const int nt = (work >> 3) & 7;              // out cols [nt*128, +128)
    const int mt = work & 7;

    const int t = threadIdx.x, lane = t & 63, w = t >> 6;
    int cnt = tpe[e]; if (cnt > CAP) cnt = CAP;
    const int m0 = mt * 128;
    if (m0 >= cnt) return;
    const int start = expert_start(tpe, e, lane);

    char* As = lds;
    char* Bs = lds + 16384;
    const int wr = w >> 1, wc = w & 1;
    const int r = lane & 15, q = lane >> 4;

    f32x4 acc[4][4];
    const f32x4 z4 = {0.f, 0.f, 0.f, 0.f};
    #pragma unroll
    for (int i = 0; i < 4; ++i)
        #pragma unroll
        for (int j = 0; j < 4; ++j) acc[i][j] = z4;

    const int swb = ((lane & 7) ^ (lane >> 3)) << 4;
    const char* aP = (const char*)hbuf;   // 1024 B rows
    const char* bP = (const char*)w2p + ((size_t)e << 20) + (size_t)(nt * 128) * 1024;

    for (int kt = 0; kt < 8; ++kt) {
        __syncthreads();
        const int kb = kt * 128;
        #pragma unroll
        for (int i = 0; i < 4; ++i) {
            const int srow = w * 32 + i * 8 + (lane >> 3);
            long ar = (long)start + m0 + srow;
            if (ar > TTOK - 1) ar = TTOK - 1;
            gload16(aP + ar * 1024 + kb + swb, As + w * 4096 + i * 1024);
            gload16(bP + (size_t)srow * 1024 + kb + swb, Bs + w * 4096 + i * 1024);
        }
        __syncthreads();
        #pragma unroll
        for (int kk = 0; kk < 2; ++kk) {
            bf16x8 af[4], bf[4];
            #pragma unroll
            for (int fm = 0; fm < 4; ++fm) {
                int row = (wr << 6) + (fm << 4) + r;
                af[fm] = *reinterpret_cast<const bf16x8*>(
                    As + row * 128 + ((kk * 64 + q * 16) ^ ((row & 7) << 4)));
            }
            #pragma unroll
            for (int fn = 0; fn < 4; ++fn) {
                int row = (wc << 6) + (fn << 4) + r;
                bf[fn] = *reinterpret_cast<const bf16x8*>(
                    Bs + row * 128 + ((kk * 64 + q * 16) ^ ((row & 7) << 4)));
            }
            #pragma unroll
            for (int fm = 0; fm < 4; ++fm)
                #pragma unroll
                for (int fn = 0; fn < 4; ++fn)
                    acc[fm][fn] = __builtin_amdgcn_mfma_f32_16x16x32_bf16(
                        af[fm], bf[fn], acc[fm][fn], 0, 0, 0);
        }
    }

    #pragma unroll
    for (int fm = 0; fm < 4; ++fm) {
        int mb = m0 + (wr << 6) + (fm << 4) + (q << 2);
        #pragma unroll
        for (int fn = 0; fn < 4; ++fn) {
            int ocol = (nt << 7) + (wc << 6) + (fn << 4) + r;
            #pragma unroll
            for (int v = 0; v < 4; ++v) {
                if (mb + v < cnt)
                    out[(size_t)(start + mb + v) * HID + ocol] = acc[fm][fn][v];
            }
        }
    }
}

extern "C" void kernel_launch(void* const* d_in, const int* in_sizes, int n_in,
                              void* d_out, int out_size, void* d_ws, size_t ws_size,
                              hipStream_t stream) {
    const float* x   = (const float*)d_in[0];
    const int*   tpe = (const int*)d_in[1];
    const float* w13 = (const float*)d_in[2];
    const float* w2  = (const float*)d_in[3];
    float* out = (float*)d_out;

    char* ws = (char*)d_ws;
    unsigned short* xbf  = (unsigned short*)(ws);                           // 67 MB
    unsigned short* hbuf = (unsigned short*)(ws + 67108864);                // 33.5 MB
    unsigned short* w13p = (unsigned short*)(ws + 67108864 + 33554432);     // 134 MB
    unsigned short* w2p  = (unsigned short*)(ws + 67108864 + 33554432 + 134217728); // 67 MB

    cvt_all_k<<<dim3(4096, 1, 1), dim3(256, 1, 1), 0, stream>>>(x, xbf, w13, w13p);
    gemm1    <<<dim3(4096, 1, 1), dim3(256, 1, 1), 0, stream>>>(xbf, tpe, w13p, hbuf, w2, w2p);
    gemm2    <<<dim3(4096, 1, 1), dim3(256, 1, 1), 0, stream>>>(hbuf, tpe, w2p, out);
}

// Round 9
// 295.326 us; speedup vs baseline: 1.0958x; 1.0958x over previous
//
#include <hip/hip_runtime.h>
#include <hip/hip_bf16.h>
#include <stdint.h>

#define NEXP 64
#define TTOK 32768
#define HID  1024
#define IMID 512
#define CAP  1024

typedef __bf16 bf16x8 __attribute__((ext_vector_type(8)));
typedef float  f32x4  __attribute__((ext_vector_type(4)));

static __device__ __forceinline__ unsigned int f2bf_u(float f) {
    __hip_bfloat16 h = __float2bfloat16(f);
    return (unsigned int)*reinterpret_cast<unsigned short*>(&h);
}
static __device__ __forceinline__ unsigned int pack2(float lo, float hi) {
    return f2bf_u(lo) | (f2bf_u(hi) << 16);
}
static __device__ __forceinline__ unsigned short f2bf_s(float f) {
    __hip_bfloat16 h = __float2bfloat16(f);
    return *reinterpret_cast<unsigned short*>(&h);
}

static __device__ __forceinline__ void gload16(const void* g, void* l) {
    __builtin_amdgcn_global_load_lds(
        (const __attribute__((address_space(1))) unsigned int*)g,
        (__attribute__((address_space(3))) unsigned int*)l,
        16, 0, 0);
}

// wave-parallel exclusive prefix: sum of tpe[i] for i < e
static __device__ __forceinline__ int expert_start(const int* tpe, int e, int lane) {
    int v = tpe[lane];
    int contrib = (lane < e) ? v : 0;
    #pragma unroll
    for (int off = 1; off < 64; off <<= 1)
        contrib += __shfl_xor(contrib, off, 64);
    return contrib;
}

// ================= merged conversion kernel (flat: 1 tile or 1 chunk / block)
// blocks [0, 16384): one 64x64 w13 transpose-convert tile each (R7 body)
// blocks [16384, 32768): one 2048-float x convert chunk each (R7 body)
__global__ __launch_bounds__(256)
void cvt_all_k(const float* __restrict__ x, unsigned short* __restrict__ xbf,
               const float* __restrict__ w13, unsigned short* __restrict__ w13p) {
    const int bid = blockIdx.x;
    const int t   = threadIdx.x;

    if (bid < 16384) {
        const int n0 = (bid & 15) * 64;
        const int k0 = ((bid >> 4) & 15) * 64;
        const int e  = bid >> 8;
        __shared__ unsigned short Tl[64][72];
        const int kl = t >> 4, nl = (t & 15) * 4;
        const float* src = w13 + ((size_t)e << 20) + (size_t)k0 * 1024 + n0;
        #pragma unroll
        for (int p = 0; p < 4; ++p) {
            int k = kl + p * 16;
            f32x4 v = *reinterpret_cast<const f32x4*>(src + (size_t)k * 1024 + nl);
            uint2 wv; wv.x = pack2(v.x, v.y); wv.y = pack2(v.z, v.w);
            *reinterpret_cast<uint2*>(&Tl[k][nl]) = wv;
        }
        __syncthreads();
        const int nloc = t >> 2, kc = (t & 3) * 16;
        const int n = n0 + nloc;
        const int icol = n & 511, isup = n >> 9;
        const int np = (icol >> 5) * 64 + isup * 32 + (icol & 31);
        unsigned int v32[8];
        #pragma unroll
        for (int j = 0; j < 8; ++j)
            v32[j] = (unsigned int)Tl[kc + 2 * j][nloc] |
                     ((unsigned int)Tl[kc + 2 * j + 1][nloc] << 16);
        unsigned short* dst = w13p + ((size_t)e << 20) + (size_t)np * 1024 + k0 + kc;
        uint4 o0 = {v32[0], v32[1], v32[2], v32[3]};
        uint4 o1 = {v32[4], v32[5], v32[6], v32[7]};
        *reinterpret_cast<uint4*>(dst)     = o0;
        *reinterpret_cast<uint4*>(dst + 8) = o1;
    } else {
        size_t i = ((size_t)(bid - 16384) * 256 + t) * 8;
        f32x4 a = *reinterpret_cast<const f32x4*>(x + i);
        f32x4 b = *reinterpret_cast<const f32x4*>(x + i + 4);
        uint4 o;
        o.x = pack2(a.x, a.y); o.y = pack2(a.z, a.w);
        o.z = pack2(b.x, b.y); o.w = pack2(b.z, b.w);
        *reinterpret_cast<uint4*>(xbf + i) = o;
    }
}

// one 64x64 transpose-convert tile of w2: fp32 [e][512k][1024n] -> bf16 [e][n][512k]
static __device__ __forceinline__ void w2_tile_cvt(const float* __restrict__ w2,
                                                   unsigned short* __restrict__ w2p,
                                                   int tile, int t, char* lds) {
    const int e  = tile >> 7;
    const int k0 = ((tile >> 4) & 7) * 64;
    const int n0 = (tile & 15) * 64;
    unsigned short (*Tl)[72] = reinterpret_cast<unsigned short(*)[72]>(lds);  // 9216 B
    const int kl = t >> 4, nl = (t & 15) * 4;
    const float* src = w2 + (size_t)e * (IMID * HID) + (size_t)k0 * 1024 + n0;
    #pragma unroll
    for (int p = 0; p < 4; ++p) {
        int k = kl + p * 16;
        f32x4 v = *reinterpret_cast<const f32x4*>(src + (size_t)k * 1024 + nl);
        uint2 wv; wv.x = pack2(v.x, v.y); wv.y = pack2(v.z, v.w);
        *reinterpret_cast<uint2*>(&Tl[k][nl]) = wv;
    }
    __syncthreads();
    const int nloc = t >> 2, kc = (t & 3) * 16;
    unsigned int v32[8];
    #pragma unroll
    for (int j = 0; j < 8; ++j)
        v32[j] = (unsigned int)Tl[kc + 2 * j][nloc] |
                 ((unsigned int)Tl[kc + 2 * j + 1][nloc] << 16);
    unsigned short* dst = w2p + (size_t)e * (HID * IMID) + (size_t)(n0 + nloc) * IMID + k0 + kc;
    uint4 o0 = {v32[0], v32[1], v32[2], v32[3]};
    uint4 o1 = {v32[4], v32[5], v32[6], v32[7]};
    *reinterpret_cast<uint4*>(dst)     = o0;
    *reinterpret_cast<uint4*>(dst + 8) = o1;
}

// ================= GEMM1: xbf[cnt,1024] x w13p -> SwiGLU -> hbuf bf16 [T,512]
// 128x128 tile, BK=64, 4 waves (2x2), all staging via global_load_lds with
// both-sides XOR swizzle. Blocks [4096, 12288) each convert ONE w2 tile.
__global__ __launch_bounds__(256, 3)
void gemm1(const unsigned short* __restrict__ xbf,
           const int* __restrict__ tpe,
           const unsigned short* __restrict__ w13p,
           unsigned short* __restrict__ hbuf,
           const float* __restrict__ w2,
           unsigned short* __restrict__ w2p) {
    __shared__ alignas(16) char lds[32768];
    const int bid = blockIdx.x;                  // 12288 blocks
    const int t = threadIdx.x, lane = t & 63, w = t >> 6;

    if (bid >= 4096) {
        // ---- dedicated w2 conversion block (8192 tiles) ----
        w2_tile_cvt(w2, w2p, bid - 4096, t, lds);
        return;
    }

    const int work = (bid & 7) * 512 + (bid >> 3);
    const int e  = work >> 6;                    // 0..63
    const int nt = (work >> 3) & 7;              // 0..7 : 128 n'-rows = 64 icols
    const int mt = work & 7;                     // 0..7

    int cnt = tpe[e]; if (cnt > CAP) cnt = CAP;
    const int m0 = mt * 128;
    if (m0 >= cnt) return;
    const int start = expert_start(tpe, e, lane);

    char* As = lds;            // [128m][64k] bf16, source-swizzled
    char* Bs = lds + 16384;    // [128n'][64k] bf16, source-swizzled
    const int wr = w >> 1, wc = w & 1;
    const int r = lane & 15, q = lane >> 4;

    f32x4 acc[4][4];
    const f32x4 z4 = {0.f, 0.f, 0.f, 0.f};
    #pragma unroll
    for (int i = 0; i < 4; ++i)
        #pragma unroll
        for (int j = 0; j < 4; ++j) acc[i][j] = z4;

    const int swb = ((lane & 7) ^ (lane >> 3)) << 4;
    const char* aP = (const char*)xbf;   // 2048 B rows
    const char* bP = (const char*)w13p + ((size_t)e << 21) + (size_t)(nt * 128) * 2048;

    for (int kt = 0; kt < 16; ++kt) {
        __syncthreads();
        const int kb = kt * 128;
        #pragma unroll
        for (int i = 0; i < 4; ++i) {
            const int srow = w * 32 + i * 8 + (lane >> 3);
            long ar = (long)start + m0 + srow;
            if (ar > TTOK - 1) ar = TTOK - 1;
            gload16(aP + ar * 2048 + kb + swb, As + w * 4096 + i * 1024);
            gload16(bP + (size_t)srow * 2048 + kb + swb, Bs + w * 4096 + i * 1024);
        }
        __syncthreads();
        #pragma unroll
        for (int kk = 0; kk < 2; ++kk) {
            bf16x8 af[4], bf[4];
            #pragma unroll
            for (int fm = 0; fm < 4; ++fm) {
                int row = (wr << 6) + (fm << 4) + r;
                af[fm] = *reinterpret_cast<const bf16x8*>(
                    As + row * 128 + ((kk * 64 + q * 16) ^ ((row & 7) << 4)));
            }
            #pragma unroll
            for (int fn = 0; fn < 4; ++fn) {
                int row = (wc << 6) + (fn << 4) + r;
                bf[fn] = *reinterpret_cast<const bf16x8*>(
                    Bs + row * 128 + ((kk * 64 + q * 16) ^ ((row & 7) << 4)));
            }
            #pragma unroll
            for (int fm = 0; fm < 4; ++fm)
                #pragma unroll
                for (int fn = 0; fn < 4; ++fn)
                    acc[fm][fn] = __builtin_amdgcn_mfma_f32_16x16x32_bf16(
                        af[fm], bf[fn], acc[fm][fn], 0, 0, 0);
        }
    }

    // SwiGLU: n' = nt*128 + wc*64 + fn*16 + r; fn<2 = gate, fn>=2 = up
    #pragma unroll
    for (int fm = 0; fm < 4; ++fm) {
        int mb = m0 + (wr << 6) + (fm << 4) + (q << 2);
        #pragma unroll
        for (int fp = 0; fp < 2; ++fp) {
            f32x4 g = acc[fm][fp];
            f32x4 u = acc[fm][fp + 2];
            int icol = (nt * 2 + wc) * 32 + fp * 16 + r;
            #pragma unroll
            for (int v = 0; v < 4; ++v) {
                if (mb + v < cnt) {
                    float gv = g[v];
                    float sv = (gv / (1.f + __expf(-gv))) * u[v];
                    hbuf[(size_t)(start + mb + v) * IMID + icol] = f2bf_s(sv);
                }
            }
        }
    }
}

// ================= GEMM2: hbuf[cnt,512] x w2p -> out fp32 [T,1024]
__global__ __launch_bounds__(256, 3)
void gemm2(const unsigned short* __restrict__ hbuf,
           const int* __restrict__ tpe,
           const unsigned short* __restrict__ w2p,
           float* __restrict__ out) {
    __shared__ alignas(16) char lds[32768];
    const int bid  = blockIdx.x;                 // 4096 blocks
    const int work = (bid & 7) * 512 + (bid >> 3);
    const int e  = work >> 6;
    const int nt = (work >> 3) & 7;              // out cols [nt*128, +128)
    const int mt = work & 7;

    const int t = threadIdx.x, lane = t & 63, w = t >> 6;
    int cnt = tpe[e]; if (cnt > CAP) cnt = CAP;
    const int m0 = mt * 128;
    if (m0 >= cnt) return;
    const int start = expert_start(tpe, e, lane);

    char* As = lds;
    char* Bs = lds + 16384;
    const int wr = w >> 1, wc = w & 1;
    const int r = lane & 15, q = lane >> 4;

    f32x4 acc[4][4];
    const f32x4 z4 = {0.f, 0.f, 0.f, 0.f};
    #pragma unroll
    for (int i = 0; i < 4; ++i)
        #pragma unroll
        for (int j = 0; j < 4; ++j) acc[i][j] = z4;

    const int swb = ((lane & 7) ^ (lane >> 3)) << 4;
    const char* aP = (const char*)hbuf;   // 1024 B rows
    const char* bP = (const char*)w2p + ((size_t)e << 20) + (size_t)(nt * 128) * 1024;

    for (int kt = 0; kt < 8; ++kt) {
        __syncthreads();
        const int kb = kt * 128;
        #pragma unroll
        for (int i = 0; i < 4; ++i) {
            const int srow = w * 32 + i * 8 + (lane >> 3);
            long ar = (long)start + m0 + srow;
            if (ar > TTOK - 1) ar = TTOK - 1;
            gload16(aP + ar * 1024 + kb + swb, As + w * 4096 + i * 1024);
            gload16(bP + (size_t)srow * 1024 + kb + swb, Bs + w * 4096 + i * 1024);
        }
        __syncthreads();
        #pragma unroll
        for (int kk = 0; kk < 2; ++kk) {
            bf16x8 af[4], bf[4];
            #pragma unroll
            for (int fm = 0; fm < 4; ++fm) {
                int row = (wr << 6) + (fm << 4) + r;
                af[fm] = *reinterpret_cast<const bf16x8*>(
                    As + row * 128 + ((kk * 64 + q * 16) ^ ((row & 7) << 4)));
            }
            #pragma unroll
            for (int fn = 0; fn < 4; ++fn) {
                int row = (wc << 6) + (fn << 4) + r;
                bf[fn] = *reinterpret_cast<const bf16x8*>(
                    Bs + row * 128 + ((kk * 64 + q * 16) ^ ((row & 7) << 4)));
            }
            #pragma unroll
            for (int fm = 0; fm < 4; ++fm)
                #pragma unroll
                for (int fn = 0; fn < 4; ++fn)
                    acc[fm][fn] = __builtin_amdgcn_mfma_f32_16x16x32_bf16(
                        af[fm], bf[fn], acc[fm][fn], 0, 0, 0);
        }
    }

    #pragma unroll
    for (int fm = 0; fm < 4; ++fm) {
        int mb = m0 + (wr << 6) + (fm << 4) + (q << 2);
        #pragma unroll
        for (int fn = 0; fn < 4; ++fn) {
            int ocol = (nt << 7) + (wc << 6) + (fn << 4) + r;
            #pragma unroll
            for (int v = 0; v < 4; ++v) {
                if (mb + v < cnt)
                    out[(size_t)(start + mb + v) * HID + ocol] = acc[fm][fn][v];
            }
        }
    }
}

extern "C" void kernel_launch(void* const* d_in, const int* in_sizes, int n_in,
                              void* d_out, int out_size, void* d_ws, size_t ws_size,
                              hipStream_t stream) {
    const float* x   = (const float*)d_in[0];
    const int*   tpe = (const int*)d_in[1];
    const float* w13 = (const float*)d_in[2];
    const float* w2  = (const float*)d_in[3];
    float* out = (float*)d_out;

    char* ws = (char*)d_ws;
    unsigned short* xbf  = (unsigned short*)(ws);                           // 67 MB
    unsigned short* hbuf = (unsigned short*)(ws + 67108864);                // 33.5 MB
    unsigned short* w13p = (unsigned short*)(ws + 67108864 + 33554432);     // 134 MB
    unsigned short* w2p  = (unsigned short*)(ws + 67108864 + 33554432 + 134217728); // 67 MB

    cvt_all_k<<<dim3(32768, 1, 1), dim3(256, 1, 1), 0, stream>>>(x, xbf, w13, w13p);
    gemm1    <<<dim3(12288, 1, 1), dim3(256, 1, 1), 0, stream>>>(xbf, tpe, w13p, hbuf, w2, w2p);
    gemm2    <<<dim3(4096, 1, 1), dim3(256, 1, 1), 0, stream>>>(hbuf, tpe, w2p, out);
}

// Round 10
// 284.610 us; speedup vs baseline: 1.1371x; 1.0377x over previous
//
#include <hip/hip_runtime.h>
#include <hip/hip_bf16.h>
#include <stdint.h>

#define NEXP 64
#define TTOK 32768
#define HID  1024
#define IMID 512
#define CAP  1024

typedef __bf16 bf16x8 __attribute__((ext_vector_type(8)));
typedef float  f32x4  __attribute__((ext_vector_type(4)));

static __device__ __forceinline__ unsigned int f2bf_u(float f) {
    __hip_bfloat16 h = __float2bfloat16(f);
    return (unsigned int)*reinterpret_cast<unsigned short*>(&h);
}
static __device__ __forceinline__ unsigned int pack2(float lo, float hi) {
    return f2bf_u(lo) | (f2bf_u(hi) << 16);
}
static __device__ __forceinline__ unsigned short f2bf_s(float f) {
    __hip_bfloat16 h = __float2bfloat16(f);
    return *reinterpret_cast<unsigned short*>(&h);
}

static __device__ __forceinline__ void gload16(const void* g, void* l) {
    __builtin_amdgcn_global_load_lds(
        (const __attribute__((address_space(1))) unsigned int*)g,
        (__attribute__((address_space(3))) unsigned int*)l,
        16, 0, 0);
}

// wave-parallel exclusive prefix: sum of tpe[i] for i < e
static __device__ __forceinline__ int expert_start(const int* tpe, int e, int lane) {
    int v = tpe[lane];
    int contrib = (lane < e) ? v : 0;
    #pragma unroll
    for (int off = 1; off < 64; off <<= 1)
        contrib += __shfl_xor(contrib, off, 64);
    return contrib;
}

// ================= merged conversion kernel (flat: 1 tile or 1 chunk / block)
// blocks [0, 16384): one 64x64 w13 transpose-convert tile each
// blocks [16384, 32768): one 2048-float x convert chunk each
__global__ __launch_bounds__(256)
void cvt_all_k(const float* __restrict__ x, unsigned short* __restrict__ xbf,
               const float* __restrict__ w13, unsigned short* __restrict__ w13p) {
    const int bid = blockIdx.x;
    const int t   = threadIdx.x;

    if (bid < 16384) {
        const int n0 = (bid & 15) * 64;
        const int k0 = ((bid >> 4) & 15) * 64;
        const int e  = bid >> 8;
        __shared__ unsigned short Tl[64][72];
        const int kl = t >> 4, nl = (t & 15) * 4;
        const float* src = w13 + ((size_t)e << 20) + (size_t)k0 * 1024 + n0;
        #pragma unroll
        for (int p = 0; p < 4; ++p) {
            int k = kl + p * 16;
            f32x4 v = *reinterpret_cast<const f32x4*>(src + (size_t)k * 1024 + nl);
            uint2 wv; wv.x = pack2(v.x, v.y); wv.y = pack2(v.z, v.w);
            *reinterpret_cast<uint2*>(&Tl[k][nl]) = wv;
        }
        __syncthreads();
        const int nloc = t >> 2, kc = (t & 3) * 16;
        const int n = n0 + nloc;
        const int icol = n & 511, isup = n >> 9;
        const int np = (icol >> 5) * 64 + isup * 32 + (icol & 31);
        unsigned int v32[8];
        #pragma unroll
        for (int j = 0; j < 8; ++j)
            v32[j] = (unsigned int)Tl[kc + 2 * j][nloc] |
                     ((unsigned int)Tl[kc + 2 * j + 1][nloc] << 16);
        unsigned short* dst = w13p + ((size_t)e << 20) + (size_t)np * 1024 + k0 + kc;
        uint4 o0 = {v32[0], v32[1], v32[2], v32[3]};
        uint4 o1 = {v32[4], v32[5], v32[6], v32[7]};
        *reinterpret_cast<uint4*>(dst)     = o0;
        *reinterpret_cast<uint4*>(dst + 8) = o1;
    } else {
        size_t i = ((size_t)(bid - 16384) * 256 + t) * 8;
        f32x4 a = *reinterpret_cast<const f32x4*>(x + i);
        f32x4 b = *reinterpret_cast<const f32x4*>(x + i + 4);
        uint4 o;
        o.x = pack2(a.x, a.y); o.y = pack2(a.z, a.w);
        o.z = pack2(b.x, b.y); o.w = pack2(b.z, b.w);
        *reinterpret_cast<uint4*>(xbf + i) = o;
    }
}

// one 64x64 transpose-convert tile of w2: fp32 [e][512k][1024n] -> bf16 [e][n][512k]
static __device__ __forceinline__ void w2_tile_cvt(const float* __restrict__ w2,
                                                   unsigned short* __restrict__ w2p,
                                                   int tile, int t, char* lds) {
    const int e  = tile >> 7;
    const int k0 = ((tile >> 4) & 7) * 64;
    const int n0 = (tile & 15) * 64;
    unsigned short (*Tl)[72] = reinterpret_cast<unsigned short(*)[72]>(lds);  // 9216 B
    const int kl = t >> 4, nl = (t & 15) * 4;
    const float* src = w2 + (size_t)e * (IMID * HID) + (size_t)k0 * 1024 + n0;
    #pragma unroll
    for (int p = 0; p < 4; ++p) {
        int k = kl + p * 16;
        f32x4 v = *reinterpret_cast<const f32x4*>(src + (size_t)k * 1024 + nl);
        uint2 wv; wv.x = pack2(v.x, v.y); wv.y = pack2(v.z, v.w);
        *reinterpret_cast<uint2*>(&Tl[k][nl]) = wv;
    }
    __syncthreads();
    const int nloc = t >> 2, kc = (t & 3) * 16;
    unsigned int v32[8];
    #pragma unroll
    for (int j = 0; j < 8; ++j)
        v32[j] = (unsigned int)Tl[kc + 2 * j][nloc] |
                 ((unsigned int)Tl[kc + 2 * j + 1][nloc] << 16);
    unsigned short* dst = w2p + (size_t)e * (HID * IMID) + (size_t)(n0 + nloc) * IMID + k0 + kc;
    uint4 o0 = {v32[0], v32[1], v32[2], v32[3]};
    uint4 o1 = {v32[4], v32[5], v32[6], v32[7]};
    *reinterpret_cast<uint4*>(dst)     = o0;
    *reinterpret_cast<uint4*>(dst + 8) = o1;
}

// ================= GEMM1: xbf[cnt,1024] x w13p -> SwiGLU -> hbuf bf16 [T,512]
// 128m x 256n' tile, BK=64, 4 waves (2x2), acc 4x8 per wave.
// All staging via global_load_lds, both-sides XOR swizzle.
// Blocks [2048, 10240) each convert ONE w2 tile.
__global__ __launch_bounds__(256, 2)
void gemm1(const unsigned short* __restrict__ xbf,
           const int* __restrict__ tpe,
           const unsigned short* __restrict__ w13p,
           unsigned short* __restrict__ hbuf,
           const float* __restrict__ w2,
           unsigned short* __restrict__ w2p) {
    __shared__ alignas(16) char lds[49152];
    const int bid = blockIdx.x;                  // 10240 blocks
    const int t = threadIdx.x, lane = t & 63, w = t >> 6;

    if (bid >= 2048) {
        w2_tile_cvt(w2, w2p, bid - 2048, t, lds);
        return;
    }

    const int work = (bid & 7) * 256 + (bid >> 3);
    const int e  = work >> 5;                    // 0..63
    const int nt = (work >> 3) & 3;              // 0..3 : 256 n'-rows
    const int mt = work & 7;                     // 0..7

    int cnt = tpe[e]; if (cnt > CAP) cnt = CAP;
    const int m0 = mt * 128;
    if (m0 >= cnt) return;
    const int start = expert_start(tpe, e, lane);

    char* As = lds;            // [128 m][64k] bf16, source-swizzled (16 KB)
    char* Bs = lds + 16384;    // [256 n'][64k] bf16, source-swizzled (32 KB)
    const int wr = w >> 1, wc = w & 1;
    const int r = lane & 15, q = lane >> 4;

    f32x4 acc[4][8];
    const f32x4 z4 = {0.f, 0.f, 0.f, 0.f};
    #pragma unroll
    for (int i = 0; i < 4; ++i)
        #pragma unroll
        for (int j = 0; j < 8; ++j) acc[i][j] = z4;

    const int swb = ((lane & 7) ^ (lane >> 3)) << 4;
    const char* aP = (const char*)xbf;   // 2048 B rows
    const char* bP = (const char*)w13p + ((size_t)e << 21) + ((size_t)nt << 19);

    for (int kt = 0; kt < 16; ++kt) {
        __syncthreads();
        const int kb = kt * 128;
        #pragma unroll
        for (int i = 0; i < 4; ++i) {
            const int srow = w * 32 + i * 8 + (lane >> 3);
            long ar = (long)start + m0 + srow;
            if (ar > TTOK - 1) ar = TTOK - 1;
            gload16(aP + ar * 2048 + kb + swb, As + w * 4096 + i * 1024);
        }
        #pragma unroll
        for (int i = 0; i < 8; ++i) {
            const int srow = w * 64 + i * 8 + (lane >> 3);
            gload16(bP + (size_t)srow * 2048 + kb + swb, Bs + w * 8192 + i * 1024);
        }
        __syncthreads();
        #pragma unroll
        for (int kk = 0; kk < 2; ++kk) {
            bf16x8 af[4], bf[8];
            #pragma unroll
            for (int fm = 0; fm < 4; ++fm) {
                int row = (wr << 6) + (fm << 4) + r;
                af[fm] = *reinterpret_cast<const bf16x8*>(
                    As + row * 128 + ((kk * 64 + q * 16) ^ ((row & 7) << 4)));
            }
            #pragma unroll
            for (int fn = 0; fn < 8; ++fn) {
                int row = (wc << 7) + (fn << 4) + r;
                bf[fn] = *reinterpret_cast<const bf16x8*>(
                    Bs + row * 128 + ((kk * 64 + q * 16) ^ ((row & 7) << 4)));
            }
            #pragma unroll
            for (int fm = 0; fm < 4; ++fm)
                #pragma unroll
                for (int fn = 0; fn < 8; ++fn)
                    acc[fm][fn] = __builtin_amdgcn_mfma_f32_16x16x32_bf16(
                        af[fm], bf[fn], acc[fm][fn], 0, 0, 0);
        }
    }

    // SwiGLU: np_global = nt*256 + wc*128 + fn*16 + r, fn = c2*4 + isup*2 + fp
    // icol = (nt*4 + wc*2 + c2)*32 + fp*16 + r
    #pragma unroll
    for (int fm = 0; fm < 4; ++fm) {
        int mb = m0 + (wr << 6) + (fm << 4) + (q << 2);
        #pragma unroll
        for (int c2 = 0; c2 < 2; ++c2) {
            #pragma unroll
            for (int fp = 0; fp < 2; ++fp) {
                f32x4 g = acc[fm][c2 * 4 + fp];
                f32x4 u = acc[fm][c2 * 4 + 2 + fp];
                int icol = (nt * 4 + wc * 2 + c2) * 32 + fp * 16 + r;
                #pragma unroll
                for (int v = 0; v < 4; ++v) {
                    if (mb + v < cnt) {
                        float gv = g[v];
                        float sv = (gv / (1.f + __expf(-gv))) * u[v];
                        hbuf[(size_t)(start + mb + v) * IMID + icol] = f2bf_s(sv);
                    }
                }
            }
        }
    }
}

// ================= GEMM2: hbuf[cnt,512] x w2p -> out fp32 [T,1024]
// 128m x 256n tile, BK=64, 4 waves (2x2), acc 4x8.
__global__ __launch_bounds__(256, 2)
void gemm2(const unsigned short* __restrict__ hbuf,
           const int* __restrict__ tpe,
           const unsigned short* __restrict__ w2p,
           float* __restrict__ out) {
    __shared__ alignas(16) char lds[49152];
    const int bid  = blockIdx.x;                 // 2048 blocks
    const int work = (bid & 7) * 256 + (bid >> 3);
    const int e  = work >> 5;
    const int nt = (work >> 3) & 3;              // out cols [nt*256, +256)
    const int mt = work & 7;

    const int t = threadIdx.x, lane = t & 63, w = t >> 6;
    int cnt = tpe[e]; if (cnt > CAP) cnt = CAP;
    const int m0 = mt * 128;
    if (m0 >= cnt) return;
    const int start = expert_start(tpe, e, lane);

    char* As = lds;            // [128 m][64k]  (16 KB)
    char* Bs = lds + 16384;    // [256 n][64k]  (32 KB)
    const int wr = w >> 1, wc = w & 1;
    const int r = lane & 15, q = lane >> 4;

    f32x4 acc[4][8];
    const f32x4 z4 = {0.f, 0.f, 0.f, 0.f};
    #pragma unroll
    for (int i = 0; i < 4; ++i)
        #pragma unroll
        for (int j = 0; j < 8; ++j) acc[i][j] = z4;

    const int swb = ((lane & 7) ^ (lane >> 3)) << 4;
    const char* aP = (const char*)hbuf;   // 1024 B rows
    const char* bP = (const char*)w2p + ((size_t)e << 20) + ((size_t)nt << 18);

    for (int kt = 0; kt < 8; ++kt) {
        __syncthreads();
        const int kb = kt * 128;
        #pragma unroll
        for (int i = 0; i < 4; ++i) {
            const int srow = w * 32 + i * 8 + (lane >> 3);
            long ar = (long)start + m0 + srow;
            if (ar > TTOK - 1) ar = TTOK - 1;
            gload16(aP + ar * 1024 + kb + swb, As + w * 4096 + i * 1024);
        }
        #pragma unroll
        for (int i = 0; i < 8; ++i) {
            const int srow = w * 64 + i * 8 + (lane >> 3);
            gload16(bP + (size_t)srow * 1024 + kb + swb, Bs + w * 8192 + i * 1024);
        }
        __syncthreads();
        #pragma unroll
        for (int kk = 0; kk < 2; ++kk) {
            bf16x8 af[4], bf[8];
            #pragma unroll
            for (int fm = 0; fm < 4; ++fm) {
                int row = (wr << 6) + (fm << 4) + r;
                af[fm] = *reinterpret_cast<const bf16x8*>(
                    As + row * 128 + ((kk * 64 + q * 16) ^ ((row & 7) << 4)));
            }
            #pragma unroll
            for (int fn = 0; fn < 8; ++fn) {
                int row = (wc << 7) + (fn << 4) + r;
                bf[fn] = *reinterpret_cast<const bf16x8*>(
                    Bs + row * 128 + ((kk * 64 + q * 16) ^ ((row & 7) << 4)));
            }
            #pragma unroll
            for (int fm = 0; fm < 4; ++fm)
                #pragma unroll
                for (int fn = 0; fn < 8; ++fn)
                    acc[fm][fn] = __builtin_amdgcn_mfma_f32_16x16x32_bf16(
                        af[fm], bf[fn], acc[fm][fn], 0, 0, 0);
        }
    }

    #pragma unroll
    for (int fm = 0; fm < 4; ++fm) {
        int mb = m0 + (wr << 6) + (fm << 4) + (q << 2);
        #pragma unroll
        for (int fn = 0; fn < 8; ++fn) {
            int ocol = (nt << 8) + (wc << 7) + (fn << 4) + r;
            #pragma unroll
            for (int v = 0; v < 4; ++v) {
                if (mb + v < cnt)
                    out[(size_t)(start + mb + v) * HID + ocol] = acc[fm][fn][v];
            }
        }
    }
}

extern "C" void kernel_launch(void* const* d_in, const int* in_sizes, int n_in,
                              void* d_out, int out_size, void* d_ws, size_t ws_size,
                              hipStream_t stream) {
    const float* x   = (const float*)d_in[0];
    const int*   tpe = (const int*)d_in[1];
    const float* w13 = (const float*)d_in[2];
    const float* w2  = (const float*)d_in[3];
    float* out = (float*)d_out;

    char* ws = (char*)d_ws;
    unsigned short* xbf  = (unsigned short*)(ws);                           // 67 MB
    unsigned short* hbuf = (unsigned short*)(ws + 67108864);                // 33.5 MB
    unsigned short* w13p = (unsigned short*)(ws + 67108864 + 33554432);     // 134 MB
    unsigned short* w2p  = (unsigned short*)(ws + 67108864 + 33554432 + 134217728); // 67 MB

    cvt_all_k<<<dim3(32768, 1, 1), dim3(256, 1, 1), 0, stream>>>(x, xbf, w13, w13p);
    gemm1    <<<dim3(10240, 1, 1), dim3(256, 1, 1), 0, stream>>>(xbf, tpe, w13p, hbuf, w2, w2p);
    gemm2    <<<dim3(2048, 1, 1), dim3(256, 1, 1), 0, stream>>>(hbuf, tpe, w2p, out);
}